// Round 1
// baseline (172.496 us; speedup 1.0000x reference)
//
#include <hip/hip_runtime.h>

// MSE_DQ_FK: dual-quaternion denorm -> local rot -> FK -> mse losses -> scalar.
// B=64, T=1024, J=22, C=176. Layout (B,C,T), T contiguous.
// Only the rotation quaternion (first 4 of each joint's 8 dq channels) is used.
// Telescoping identity: rots[j] = conj(q0n) * qjn  (local[0] forced identity,
// unit-norm cancellation); for ik/dec chains q0 = identity -> rots[j] = qjn.

#define T_DIM 1024

struct Q { float w, x, y, z; };
struct V3 { float x, y, z; };

__device__ __forceinline__ Q qmul(const Q a, const Q b) {
    Q r;
    r.w = a.w*b.w - a.x*b.x - a.y*b.y - a.z*b.z;
    r.x = a.w*b.x + a.x*b.w + a.y*b.z - a.z*b.y;
    r.y = a.w*b.y - a.x*b.z + a.y*b.w + a.z*b.x;
    r.z = a.w*b.z + a.x*b.y - a.y*b.x + a.z*b.w;
    return r;
}

__device__ __forceinline__ V3 qrot(const Q q, const V3 v) {
    // t = 2*cross(qv, v); out = v + w*t + cross(qv, t)
    float tx = 2.f*(q.y*v.z - q.z*v.y);
    float ty = 2.f*(q.z*v.x - q.x*v.z);
    float tz = 2.f*(q.x*v.y - q.y*v.x);
    V3 r;
    r.x = v.x + q.w*tx + (q.y*tz - q.z*ty);
    r.y = v.y + q.w*ty + (q.z*tx - q.x*tz);
    r.z = v.z + q.w*tz + (q.x*ty - q.y*tx);
    return r;
}

__device__ __forceinline__ V3 v3add(const V3 a, const V3 b) {
    return V3{a.x+b.x, a.y+b.y, a.z+b.z};
}

__device__ __forceinline__ void qmat(const Q q, float m[9]) {
    float xx=q.x*q.x, yy=q.y*q.y, zz=q.z*q.z;
    float xy=q.x*q.y, xz=q.x*q.z, yz=q.y*q.z;
    float wx=q.w*q.x, wy=q.w*q.y, wz=q.w*q.z;
    m[0]=1.f-2.f*(yy+zz); m[1]=2.f*(xy-wz);     m[2]=2.f*(xz+wy);
    m[3]=2.f*(xy+wz);     m[4]=1.f-2.f*(xx+zz); m[5]=2.f*(yz-wx);
    m[6]=2.f*(xz-wy);     m[7]=2.f*(yz+wx);     m[8]=1.f-2.f*(xx+yy);
}

__device__ __forceinline__ float rmdiff2(const Q a, const Q b) {
    float ma[9], mb[9];
    qmat(a, ma); qmat(b, mb);
    float s = 0.f;
#pragma unroll
    for (int i = 0; i < 9; ++i) { float d = ma[i]-mb[i]; s += d*d; }
    return s;
}

__device__ __forceinline__ float pdiff2(const V3 a, const V3 b) {
    float dx=a.x-b.x, dy=a.y-b.y, dz=a.z-b.z;
    return dx*dx+dy*dy+dz*dz;
}

// Load 4 channel-strided floats, denormalize, normalize to unit quat.
__device__ __forceinline__ Q loadq_norm(const float* __restrict__ p,
                                        const float* __restrict__ sm,
                                        const float* __restrict__ ss) {
    Q q;
    q.w = p[0*T_DIM]*ss[0]+sm[0];
    q.x = p[1*T_DIM]*ss[1]+sm[1];
    q.y = p[2*T_DIM]*ss[2]+sm[2];
    q.z = p[3*T_DIM]*ss[3]+sm[3];
    float inv = rsqrtf(q.w*q.w+q.x*q.x+q.y*q.y+q.z*q.z);
    q.w*=inv; q.x*=inv; q.y*=inv; q.z*=inv;
    return q;
}

struct St { Q rot; V3 pos; };

// One joint step for all three chains. EE joints: ik-vs-tgt loss;
// non-sparse joints: dec-vs-ik loss. Joint 0 contributes to neither.
template<int J, bool EE>
__device__ __forceinline__ void step(
    St& sik, St& sde, St& stg,
    const float* __restrict__ ikp, const float* __restrict__ dep,
    const float* __restrict__ tgp,
    const float* __restrict__ sm, const float* __restrict__ ss,
    const float* __restrict__ so, const Q q0c,
    float& aep, float& aer, float& arp, float& arr)
{
    const int c0 = J*8;
    Q qik = loadq_norm(ikp + (c0-8)*T_DIM, sm+c0, ss+c0);
    Q qde = loadq_norm(dep +  c0   *T_DIM, sm+c0, ss+c0);
    Q qtg = loadq_norm(tgp +  c0   *T_DIM, sm+c0, ss+c0);
    V3 off = { so[3*J], so[3*J+1], so[3*J+2] };
    V3 pik = v3add(qrot(sik.rot, off), sik.pos);
    V3 pde = v3add(qrot(sde.rot, off), sde.pos);
    V3 ptg = v3add(qrot(stg.rot, off), stg.pos);
    Q rtg = qmul(q0c, qtg);   // tgt root is not identity
    if (EE) {
        aep += pdiff2(pik, ptg);
        aer += rmdiff2(qik, rtg);
    } else {
        arp += pdiff2(pde, pik);
        arr += rmdiff2(qde, qik);
    }
    sik.rot = qik; sik.pos = pik;
    sde.rot = qde; sde.pos = pde;
    stg.rot = rtg; stg.pos = ptg;
}

__global__ __launch_bounds__(256, 1) void fk_loss_kernel(
    const float* __restrict__ ik, const float* __restrict__ dec,
    const float* __restrict__ tgt, const float* __restrict__ mean,
    const float* __restrict__ stdv, const float* __restrict__ offs,
    float* __restrict__ out)
{
    __shared__ float sm[176], ss[176], so[66];
    __shared__ float swred[4];
    const int tid = threadIdx.x;
    if (tid < 176) { sm[tid] = mean[tid]; ss[tid] = stdv[tid]; }
    if (tid < 66) so[tid] = offs[tid];
    __syncthreads();

    const int p = blockIdx.x * 256 + tid;
    const int b = p >> 10;          // / T
    const int t = p & 1023;         // % T
    const float* ikp = ik  + (size_t)b * (168*1024) + t;
    const float* dep = dec + (size_t)b * (176*1024) + t;
    const float* tgp = tgt + (size_t)b * (176*1024) + t;

    float aep=0.f, aer=0.f, arp=0.f, arr=0.f;

    // target chain root quaternion (denorm + normalize), conjugated
    Q q0 = loadq_norm(tgp, sm, ss);
    Q q0c = { q0.w, -q0.x, -q0.y, -q0.z };

    const St root = { {1.f,0.f,0.f,0.f}, {0.f,0.f,0.f} };
    St sik, sde, stg;

    // PARENTS = [0,0,1,2,3, 0,5,6,7, 0,9,10,11,12, 11,14,15,16, 11,18,19,20]
    // chain A: 1-2-3-4 (4 is EE)
    sik = root; sde = root; stg = root;
    step<1,false>(sik,sde,stg, ikp,dep,tgp, sm,ss,so, q0c, aep,aer,arp,arr);
    step<2,false>(sik,sde,stg, ikp,dep,tgp, sm,ss,so, q0c, aep,aer,arp,arr);
    step<3,false>(sik,sde,stg, ikp,dep,tgp, sm,ss,so, q0c, aep,aer,arp,arr);
    step<4,true >(sik,sde,stg, ikp,dep,tgp, sm,ss,so, q0c, aep,aer,arp,arr);
    // chain B: 5-6-7-8 (8 is EE)
    sik = root; sde = root; stg = root;
    step<5,false>(sik,sde,stg, ikp,dep,tgp, sm,ss,so, q0c, aep,aer,arp,arr);
    step<6,false>(sik,sde,stg, ikp,dep,tgp, sm,ss,so, q0c, aep,aer,arp,arr);
    step<7,false>(sik,sde,stg, ikp,dep,tgp, sm,ss,so, q0c, aep,aer,arp,arr);
    step<8,true >(sik,sde,stg, ikp,dep,tgp, sm,ss,so, q0c, aep,aer,arp,arr);
    // chain C: 9-10-11, branch point at 11
    sik = root; sde = root; stg = root;
    step<9,false> (sik,sde,stg, ikp,dep,tgp, sm,ss,so, q0c, aep,aer,arp,arr);
    step<10,false>(sik,sde,stg, ikp,dep,tgp, sm,ss,so, q0c, aep,aer,arp,arr);
    step<11,false>(sik,sde,stg, ikp,dep,tgp, sm,ss,so, q0c, aep,aer,arp,arr);
    St sik11 = sik, sde11 = sde, stg11 = stg;
    // 12-13 (13 is EE)
    step<12,false>(sik,sde,stg, ikp,dep,tgp, sm,ss,so, q0c, aep,aer,arp,arr);
    step<13,true >(sik,sde,stg, ikp,dep,tgp, sm,ss,so, q0c, aep,aer,arp,arr);
    // 14-15-16-17 (17 is EE)
    sik = sik11; sde = sde11; stg = stg11;
    step<14,false>(sik,sde,stg, ikp,dep,tgp, sm,ss,so, q0c, aep,aer,arp,arr);
    step<15,false>(sik,sde,stg, ikp,dep,tgp, sm,ss,so, q0c, aep,aer,arp,arr);
    step<16,false>(sik,sde,stg, ikp,dep,tgp, sm,ss,so, q0c, aep,aer,arp,arr);
    step<17,true >(sik,sde,stg, ikp,dep,tgp, sm,ss,so, q0c, aep,aer,arp,arr);
    // 18-19-20-21 (21 is EE)
    sik = sik11; sde = sde11; stg = stg11;
    step<18,false>(sik,sde,stg, ikp,dep,tgp, sm,ss,so, q0c, aep,aer,arp,arr);
    step<19,false>(sik,sde,stg, ikp,dep,tgp, sm,ss,so, q0c, aep,aer,arp,arr);
    step<20,false>(sik,sde,stg, ikp,dep,tgp, sm,ss,so, q0c, aep,aer,arp,arr);
    step<21,true >(sik,sde,stg, ikp,dep,tgp, sm,ss,so, q0c, aep,aer,arp,arr);

    // loss = ee_pos/ (B*T*5*3) + ee_rm/(B*T*5*9)
    //      + 0.1*( reg_pos/(B*T*16*3) + reg_rm/(B*T*16*9) )
    const float BT = 65536.f;
    float loss = aep * (1.0f/(BT*15.f))
               + aer * (1.0f/(BT*45.f))
               + arp * (0.1f/(BT*48.f))
               + arr * (0.1f/(BT*144.f));

    // wave(64) shuffle reduce -> cross-wave via LDS -> one atomic per block
#pragma unroll
    for (int o = 32; o > 0; o >>= 1) loss += __shfl_down(loss, o);
    if ((tid & 63) == 0) swred[tid >> 6] = loss;
    __syncthreads();
    if (tid == 0) {
        atomicAdd(out, swred[0]+swred[1]+swred[2]+swred[3]);
    }
}

__global__ void zero_kernel(float* __restrict__ out) {
    if (threadIdx.x == 0) out[0] = 0.f;
}

extern "C" void kernel_launch(void* const* d_in, const int* in_sizes, int n_in,
                              void* d_out, int out_size, void* d_ws, size_t ws_size,
                              hipStream_t stream) {
    // inputs (setup_inputs order): input(unused), input_ik, input_decoder,
    // target, mean_dqs, std_dqs, offsets
    const float* ik   = (const float*)d_in[1];
    const float* dec  = (const float*)d_in[2];
    const float* tgt  = (const float*)d_in[3];
    const float* mean = (const float*)d_in[4];
    const float* stdv = (const float*)d_in[5];
    const float* offs = (const float*)d_in[6];
    float* out = (float*)d_out;

    zero_kernel<<<1, 64, 0, stream>>>(out);
    // 64*1024 poses / 256 threads = 256 blocks
    fk_loss_kernel<<<256, 256, 0, stream>>>(ik, dec, tgt, mean, stdv, offs, out);
}

// Round 2
// 171.711 us; speedup vs baseline: 1.0046x; 1.0046x over previous
//
#include <hip/hip_runtime.h>

// MSE_DQ_FK: dual-quaternion denorm -> local rot -> FK -> mse losses -> scalar.
// B=64, T=1024, J=22, C=176. Layout (B,C,T), T contiguous -> thread-per-t
// gives coalesced 256B/wave loads. Only rotation quats (4 of 8 dq channels)
// are read. Telescoping identity: global rot[j] = conj(q0n) * qjn (local[0]
// forced identity + unit-norm cancellation); ik/dec roots are identity.
//
// Round-2 structure: software-pipelined per-chain register prefetch (stay
// under vmcnt=63), mean/std/offsets read via uniform global indices
// (compiler scalarizes to s_load), no LDS staging.

#define T_DIM 1024

struct Q { float w, x, y, z; };
struct V3 { float x, y, z; };
struct St { Q rot; V3 pos; };

__device__ __forceinline__ Q qmul(const Q a, const Q b) {
    Q r;
    r.w = a.w*b.w - a.x*b.x - a.y*b.y - a.z*b.z;
    r.x = a.w*b.x + a.x*b.w + a.y*b.z - a.z*b.y;
    r.y = a.w*b.y - a.x*b.z + a.y*b.w + a.z*b.x;
    r.z = a.w*b.z + a.x*b.y - a.y*b.x + a.z*b.w;
    return r;
}

__device__ __forceinline__ V3 qrot(const Q q, const V3 v) {
    float tx = 2.f*(q.y*v.z - q.z*v.y);
    float ty = 2.f*(q.z*v.x - q.x*v.z);
    float tz = 2.f*(q.x*v.y - q.y*v.x);
    V3 r;
    r.x = v.x + q.w*tx + (q.y*tz - q.z*ty);
    r.y = v.y + q.w*ty + (q.z*tx - q.x*tz);
    r.z = v.z + q.w*tz + (q.x*ty - q.y*tx);
    return r;
}

__device__ __forceinline__ void qmat(const Q q, float m[9]) {
    float xx=q.x*q.x, yy=q.y*q.y, zz=q.z*q.z;
    float xy=q.x*q.y, xz=q.x*q.z, yz=q.y*q.z;
    float wx=q.w*q.x, wy=q.w*q.y, wz=q.w*q.z;
    m[0]=1.f-2.f*(yy+zz); m[1]=2.f*(xy-wz);     m[2]=2.f*(xz+wy);
    m[3]=2.f*(xy+wz);     m[4]=1.f-2.f*(xx+zz); m[5]=2.f*(yz-wx);
    m[6]=2.f*(xz-wy);     m[7]=2.f*(yz+wx);     m[8]=1.f-2.f*(xx+yy);
}

__device__ __forceinline__ float rmdiff2(const Q a, const Q b) {
    float ma[9], mb[9];
    qmat(a, ma); qmat(b, mb);
    float s = 0.f;
#pragma unroll
    for (int i = 0; i < 9; ++i) { float d = ma[i]-mb[i]; s += d*d; }
    return s;
}

__device__ __forceinline__ float pdiff2(const V3 a, const V3 b) {
    float dx=a.x-b.x, dy=a.y-b.y, dz=a.z-b.z;
    return dx*dx+dy*dy+dz*dz;
}

__device__ __forceinline__ V3 v3add(const V3 a, const V3 b) {
    return V3{a.x+b.x, a.y+b.y, a.z+b.z};
}

// Denorm raw quat channels (c0..c0+3) then normalize. mean/stdv indexed with
// compile-time-uniform c0 -> scalar loads.
__device__ __forceinline__ Q mkq(const float r[4], const int c0,
                                 const float* __restrict__ mean,
                                 const float* __restrict__ stdv) {
    Q q;
    q.w = r[0]*stdv[c0+0] + mean[c0+0];
    q.x = r[1]*stdv[c0+1] + mean[c0+1];
    q.y = r[2]*stdv[c0+2] + mean[c0+2];
    q.z = r[3]*stdv[c0+3] + mean[c0+3];
    float inv = rsqrtf(q.w*q.w + q.x*q.x + q.y*q.y + q.z*q.z);
    q.w*=inv; q.x*=inv; q.y*=inv; q.z*=inv;
    return q;
}

// Prefetch raw channel dwords for joints J0..J0+N-1 (all three streams) into
// register arrays. 12 loads/joint; chains are 4-5 joints -> 48-60 outstanding.
template<int J0, int N>
__device__ __forceinline__ void prefetch_chain(
    const float* __restrict__ ikp, const float* __restrict__ dep,
    const float* __restrict__ tgp,
    float (*ikr)[4], float (*der)[4], float (*tgr)[4])
{
#pragma unroll
    for (int jj = 0; jj < N; ++jj) {
        const int j = J0 + jj;
#pragma unroll
        for (int c = 0; c < 4; ++c) {
            ikr[jj][c] = ikp[((j-1)*8 + c)*T_DIM];   // ik array lacks root joint
            der[jj][c] = dep[(j*8 + c)*T_DIM];
            tgr[jj][c] = tgp[(j*8 + c)*T_DIM];
        }
    }
}

// One joint step for all three chains from prefetched raw data.
// EE joints: ik-vs-tgt loss; non-sparse joints: dec-vs-ik loss.
template<int J, bool EE>
__device__ __forceinline__ void stepr(
    St& sik, St& sde, St& stg,
    const float ikr[4], const float der[4], const float tgr[4],
    const float* __restrict__ mean, const float* __restrict__ stdv,
    const float* __restrict__ offs, const Q q0c,
    float& aep, float& aer, float& arp, float& arr)
{
    const int c0 = J*8;
    Q qik = mkq(ikr, c0, mean, stdv);
    Q qde = mkq(der, c0, mean, stdv);
    Q qtg = mkq(tgr, c0, mean, stdv);
    V3 off = { offs[3*J], offs[3*J+1], offs[3*J+2] };
    V3 pik = v3add(qrot(sik.rot, off), sik.pos);
    V3 pde = v3add(qrot(sde.rot, off), sde.pos);
    V3 ptg = v3add(qrot(stg.rot, off), stg.pos);
    Q rtg = qmul(q0c, qtg);   // tgt root quat is not identity
    if (EE) {
        aep += pdiff2(pik, ptg);
        aer += rmdiff2(qik, rtg);
    } else {
        arp += pdiff2(pde, pik);
        arr += rmdiff2(qde, qik);
    }
    sik.rot = qik; sik.pos = pik;
    sde.rot = qde; sde.pos = pde;
    stg.rot = rtg; stg.pos = ptg;
}

__global__ __launch_bounds__(256, 1) void fk_loss_kernel(
    const float* __restrict__ ik, const float* __restrict__ dec,
    const float* __restrict__ tgt, const float* __restrict__ mean,
    const float* __restrict__ stdv, const float* __restrict__ offs,
    float* __restrict__ out)
{
    __shared__ float swred[4];
    const int tid = threadIdx.x;
    const int p = blockIdx.x * 256 + tid;
    const int b = p >> 10;          // / T
    const int t = p & 1023;         // % T
    const float* ikp = ik  + (size_t)b * (168*1024) + t;
    const float* dep = dec + (size_t)b * (176*1024) + t;
    const float* tgp = tgt + (size_t)b * (176*1024) + t;

    float aep=0.f, aer=0.f, arp=0.f, arr=0.f;

    // PARENTS = [0,0,1,2,3, 0,5,6,7, 0,9,10,11,12, 11,14,15,16, 11,18,19,20]
    // Chains: A=1..4(EE4) B=5..8(EE8) C=9..13(EE13,branch@11) D=14..17(EE17)
    //         E=18..21(EE21)
    float Aik[4][4], Ade[4][4], Atg[4][4];
    float Bik[4][4], Bde[4][4], Btg[4][4];
    float Cik[5][4], Cde[5][4], Ctg[5][4];
    float Dik[4][4], Dde[4][4], Dtg[4][4];
    float Eik[4][4], Ede[4][4], Etg[4][4];
    float rq0[4];

    // Pipeline: issue q0+A+B, then compute chain k while chain k+1 streams.
#pragma unroll
    for (int c = 0; c < 4; ++c) rq0[c] = tgp[c*T_DIM];
    prefetch_chain<1,4>(ikp, dep, tgp, Aik, Ade, Atg);
    prefetch_chain<5,4>(ikp, dep, tgp, Bik, Bde, Btg);

    Q q0 = mkq(rq0, 0, mean, stdv);
    const Q q0c = { q0.w, -q0.x, -q0.y, -q0.z };
    const St root = { {1.f,0.f,0.f,0.f}, {0.f,0.f,0.f} };
    St sik, sde, stg;

    // chain A
    sik = root; sde = root; stg = root;
    stepr<1,false>(sik,sde,stg, Aik[0],Ade[0],Atg[0], mean,stdv,offs, q0c, aep,aer,arp,arr);
    stepr<2,false>(sik,sde,stg, Aik[1],Ade[1],Atg[1], mean,stdv,offs, q0c, aep,aer,arp,arr);
    stepr<3,false>(sik,sde,stg, Aik[2],Ade[2],Atg[2], mean,stdv,offs, q0c, aep,aer,arp,arr);
    stepr<4,true >(sik,sde,stg, Aik[3],Ade[3],Atg[3], mean,stdv,offs, q0c, aep,aer,arp,arr);

    prefetch_chain<9,5>(ikp, dep, tgp, Cik, Cde, Ctg);

    // chain B
    sik = root; sde = root; stg = root;
    stepr<5,false>(sik,sde,stg, Bik[0],Bde[0],Btg[0], mean,stdv,offs, q0c, aep,aer,arp,arr);
    stepr<6,false>(sik,sde,stg, Bik[1],Bde[1],Btg[1], mean,stdv,offs, q0c, aep,aer,arp,arr);
    stepr<7,false>(sik,sde,stg, Bik[2],Bde[2],Btg[2], mean,stdv,offs, q0c, aep,aer,arp,arr);
    stepr<8,true >(sik,sde,stg, Bik[3],Bde[3],Btg[3], mean,stdv,offs, q0c, aep,aer,arp,arr);

    prefetch_chain<14,4>(ikp, dep, tgp, Dik, Dde, Dtg);

    // chain C: 9-10-11 (branch point 11), then 12-13
    sik = root; sde = root; stg = root;
    stepr<9, false>(sik,sde,stg, Cik[0],Cde[0],Ctg[0], mean,stdv,offs, q0c, aep,aer,arp,arr);
    stepr<10,false>(sik,sde,stg, Cik[1],Cde[1],Ctg[1], mean,stdv,offs, q0c, aep,aer,arp,arr);
    stepr<11,false>(sik,sde,stg, Cik[2],Cde[2],Ctg[2], mean,stdv,offs, q0c, aep,aer,arp,arr);
    const St sik11 = sik, sde11 = sde, stg11 = stg;
    stepr<12,false>(sik,sde,stg, Cik[3],Cde[3],Ctg[3], mean,stdv,offs, q0c, aep,aer,arp,arr);
    stepr<13,true >(sik,sde,stg, Cik[4],Cde[4],Ctg[4], mean,stdv,offs, q0c, aep,aer,arp,arr);

    prefetch_chain<18,4>(ikp, dep, tgp, Eik, Ede, Etg);

    // chain D: 14-17 from branch point
    sik = sik11; sde = sde11; stg = stg11;
    stepr<14,false>(sik,sde,stg, Dik[0],Dde[0],Dtg[0], mean,stdv,offs, q0c, aep,aer,arp,arr);
    stepr<15,false>(sik,sde,stg, Dik[1],Dde[1],Dtg[1], mean,stdv,offs, q0c, aep,aer,arp,arr);
    stepr<16,false>(sik,sde,stg, Dik[2],Dde[2],Dtg[2], mean,stdv,offs, q0c, aep,aer,arp,arr);
    stepr<17,true >(sik,sde,stg, Dik[3],Dde[3],Dtg[3], mean,stdv,offs, q0c, aep,aer,arp,arr);

    // chain E: 18-21 from branch point
    sik = sik11; sde = sde11; stg = stg11;
    stepr<18,false>(sik,sde,stg, Eik[0],Ede[0],Etg[0], mean,stdv,offs, q0c, aep,aer,arp,arr);
    stepr<19,false>(sik,sde,stg, Eik[1],Ede[1],Etg[1], mean,stdv,offs, q0c, aep,aer,arp,arr);
    stepr<20,false>(sik,sde,stg, Eik[2],Ede[2],Etg[2], mean,stdv,offs, q0c, aep,aer,arp,arr);
    stepr<21,true >(sik,sde,stg, Eik[3],Ede[3],Etg[3], mean,stdv,offs, q0c, aep,aer,arp,arr);

    // loss = ee_pos/(B*T*5*3) + ee_rm/(B*T*5*9)
    //      + 0.1*( reg_pos/(B*T*16*3) + reg_rm/(B*T*16*9) )
    const float BT = 65536.f;
    float loss = aep * (1.0f/(BT*15.f))
               + aer * (1.0f/(BT*45.f))
               + arp * (0.1f/(BT*48.f))
               + arr * (0.1f/(BT*144.f));

    // wave(64) shuffle reduce -> cross-wave via LDS -> one atomic per block
#pragma unroll
    for (int o = 32; o > 0; o >>= 1) loss += __shfl_down(loss, o);
    if ((tid & 63) == 0) swred[tid >> 6] = loss;
    __syncthreads();
    if (tid == 0) {
        atomicAdd(out, swred[0]+swred[1]+swred[2]+swred[3]);
    }
}

extern "C" void kernel_launch(void* const* d_in, const int* in_sizes, int n_in,
                              void* d_out, int out_size, void* d_ws, size_t ws_size,
                              hipStream_t stream) {
    // inputs (setup_inputs order): input(unused), input_ik, input_decoder,
    // target, mean_dqs, std_dqs, offsets
    const float* ikx  = (const float*)d_in[1];
    const float* dec  = (const float*)d_in[2];
    const float* tgt  = (const float*)d_in[3];
    const float* mean = (const float*)d_in[4];
    const float* stdv = (const float*)d_in[5];
    const float* offs = (const float*)d_in[6];
    float* out = (float*)d_out;

    hipMemsetAsync(out, 0, sizeof(float), stream);
    // 64*1024 poses / 256 threads = 256 blocks (1 block/CU, 1 wave/SIMD)
    fk_loss_kernel<<<256, 256, 0, stream>>>(ikx, dec, tgt, mean, stdv, offs, out);
}